// Round 9
// baseline (1084.825 us; speedup 1.0000x reference)
//
#include <hip/hip_runtime.h>
#include <hip/hip_bf16.h>
#include <math.h>

#define NN 50000
#define NE 800000
#define FF 64
#define ZD 192

typedef __attribute__((ext_vector_type(8))) short bf16x8;
typedef __attribute__((ext_vector_type(4))) float f32x4;

__device__ __forceinline__ short f2bs(float f){
  union { __hip_bfloat16 h; short s; } u; u.h = __float2bfloat16(f); return u.s;
}
__device__ __forceinline__ unsigned packbf(float a, float b){
  return ((unsigned)(unsigned short)f2bs(b) << 16) | (unsigned)(unsigned short)f2bs(a);
}
__device__ __forceinline__ float lo16f(unsigned u){ union{unsigned u; float f;} v; v.u = u << 16; return v.f; }
__device__ __forceinline__ float hi16f(unsigned u){ union{unsigned u; float f;} v; v.u = u & 0xFFFF0000u; return v.f; }
__device__ __forceinline__ float sigm(float x){ return 1.0f/(1.0f+__expf(-x)); }
__device__ __forceinline__ float sofp(float x){ return fmaxf(x,0.0f)+__logf(1.0f+__expf(-fabsf(x))); }
__device__ __forceinline__ float fsilu(float x){ return x/(1.0f+__expf(-x)); }

// ---------------------------------------------------------------------------
// CSR build by dst.  kscat2 also pre-gathers per-slot metadata so the hot
// kernels read it sequentially:  meta[slot] = {eid, src, dst, dist_bits}.
// Slot order within a node is atomic-nondeterministic -> f32 sum-order noise.
// ---------------------------------------------------------------------------
__global__ __launch_bounds__(256) void kz(int* __restrict__ cnt){
  int i = blockIdx.x*256 + threadIdx.x;
  if (i < NN) cnt[i] = 0;
}
__global__ __launch_bounds__(256) void kh(const int* __restrict__ eidx, int* __restrict__ cnt){
  int e = blockIdx.x*256 + threadIdx.x;
  if (e < NE) atomicAdd(&cnt[eidx[NE + e]], 1);
}
#define SCHUNK 49
__global__ __launch_bounds__(1024) void kscan(const int* __restrict__ cnt,
                                              int* __restrict__ off, int* __restrict__ cur){
  __shared__ int bs[1024];
  int t = threadIdx.x;
  int base = t * SCHUNK;
  int s = 0;
  for (int i = 0; i < SCHUNK; i++){ int idx = base + i; if (idx < NN) s += cnt[idx]; }
  bs[t] = s;
  for (int d = 1; d < 1024; d <<= 1){
    __syncthreads();
    int u = (t >= d) ? bs[t-d] : 0;
    __syncthreads();
    bs[t] += u;
  }
  __syncthreads();
  int run = bs[t] - s;
  for (int i = 0; i < SCHUNK; i++){
    int idx = base + i;
    if (idx < NN){ off[idx] = run; cur[idx] = run; run += cnt[idx]; }
  }
}
__global__ __launch_bounds__(256) void kscat2(const int* __restrict__ eidx,
                                              const float* __restrict__ dist,
                                              int* __restrict__ cur, int4* __restrict__ meta){
  int e = blockIdx.x*256 + threadIdx.x;
  if (e < NE){
    int d = eidx[NE + e];
    int slot = atomicAdd(&cur[d], 1);
    meta[slot] = make_int4(e, eidx[e], d, __float_as_int(dist[e]));
  }
}

// ---------------------------------------------------------------------------
// k1: aout = atom copy + per-node gating-linear parts via MFMA (packed bf16).
//  P2u[n*128 + o] = pack(Af,As) ; P2u[n*128+64+o] = pack(Bf,Bs)
// ---------------------------------------------------------------------------
__global__ __launch_bounds__(256) void k1_node_pre(
    const float* __restrict__ atom,
    const float* __restrict__ wf, const float* __restrict__ ws,
    unsigned* __restrict__ P2u, float* __restrict__ aout)
{
  int tid0 = blockIdx.x * 256 + threadIdx.x;
  int nthr = gridDim.x * 256;
  const float4* a4 = (const float4*)atom;
  float4* o4 = (float4*)aout;
  for (int i = tid0; i < NN*FF/4; i += nthr) o4[i] = a4[i];

  int lane = threadIdx.x & 63;
  int c = lane & 15, kb = lane >> 4;
  int wid = blockIdx.x * 4 + (threadIdx.x >> 6);
  int nw = gridDim.x * 4;
  for (int g = wid; g < NN/16; g += nw) {
    int n0 = g * 16;
    const float* arow = &atom[(size_t)(n0 + c) * FF + kb*8];
    bf16x8 A0, A1;
    #pragma unroll
    for (int j = 0; j < 8; j++) { A0[j] = f2bs(arow[j]); A1[j] = f2bs(arow[32+j]); }
    f32x4 acc[16];
    #pragma unroll
    for (int t = 0; t < 16; t++) acc[t] = (f32x4){0,0,0,0};
    #pragma unroll
    for (int t = 0; t < 16; t++) {
      int og = t*16 + c;
      const float* src;
      if (t < 4)       src = &wf[og*ZD];
      else if (t < 8)  src = &wf[(og-64)*ZD + 64];
      else if (t < 12) src = &ws[(og-128)*ZD];
      else             src = &ws[(og-192)*ZD + 64];
      bf16x8 B0, B1;
      #pragma unroll
      for (int j = 0; j < 8; j++) { B0[j] = f2bs(src[kb*8+j]); B1[j] = f2bs(src[32+kb*8+j]); }
      acc[t] = __builtin_amdgcn_mfma_f32_16x16x32_bf16(A0, B0, acc[t], 0,0,0);
      acc[t] = __builtin_amdgcn_mfma_f32_16x16x32_bf16(A1, B1, acc[t], 0,0,0);
    }
    #pragma unroll
    for (int t = 0; t < 8; t++) {
      #pragma unroll
      for (int r = 0; r < 4; r++) {
        int n = n0 + kb*4 + r;
        P2u[(size_t)n*128 + t*16 + c] = packbf(acc[t][r], acc[t+8][r]);
      }
    }
  }
}

// ---------------------------------------------------------------------------
// k2: CSR-ordered edge-major message kernel (R5 monolith shape, slot walk).
//  Consecutive slots share dst -> P2u-dst L2-hot, atomics line-clustered.
//  fc1-stash written to compact slot-ordered stash_s (sequential 64B rows).
// ---------------------------------------------------------------------------
__global__ __launch_bounds__(256) void k2_msg(
    const int4* __restrict__ meta, const float* __restrict__ efea,
    const float* __restrict__ wf, const float* __restrict__ ws,
    const float* __restrict__ bfb, const float* __restrict__ bsb,
    const float* __restrict__ fc1w,
    const unsigned* __restrict__ P2u, float* __restrict__ aout,
    float* __restrict__ stash_s)
{
  int tid = threadIdx.x;
  int lane = tid & 63;
  int lw = tid >> 6;
  int c = lane & 15, kb = lane >> 4;

  bf16x8 Bf[9][2];
  #pragma unroll
  for (int t = 0; t < 9; t++) {
    int og = t*16 + c;
    const float* src = nullptr;
    if (t < 4)            src = &wf[og*ZD + 128];
    else if (t < 8)       src = &ws[(og-64)*ZD + 128];
    else if (og-128 < 14) src = &fc1w[(og-128)*ZD + 128];
    #pragma unroll
    for (int f = 0; f < 2; f++) {
      bf16x8 r;
      #pragma unroll
      for (int j = 0; j < 8; j++) r[j] = src ? f2bs(src[f*32 + kb*8 + j]) : (short)0;
      Bf[t][f] = r;
    }
  }
  float bfo[4], bso[4];
  #pragma unroll
  for (int t = 0; t < 4; t++) { bfo[t] = bfb[t*16+c]; bso[t] = bsb[t*16+c]; }

  int wid = blockIdx.x*4 + lw;
  int nw = gridDim.x*4;
  for (int g = wid; g < NE/16; g += nw) {
    int s0 = g*16;
    // sequential metadata: lane reads slot s0 + c
    int4 mv = meta[s0 + c];
    int   eidv = mv.x, sNv = mv.y, dNv = mv.z;
    float dev = __int_as_float(mv.w);
    float wdv = __expf(-dev*dev*(1.0f/18.0f));

    // efea gather by eid (full 256B rows, 2 lines each)
    const float* erow = &efea[(size_t)eidv*FF + kb*8];
    bf16x8 A0, A1;
    #pragma unroll
    for (int j = 0; j < 8; j++) { A0[j] = f2bs(erow[j]); A1[j] = f2bs(erow[32+j]); }
    f32x4 acc[9];
    #pragma unroll
    for (int t = 0; t < 9; t++) acc[t] = (f32x4){0,0,0,0};
    #pragma unroll
    for (int t = 0; t < 9; t++) {
      acc[t] = __builtin_amdgcn_mfma_f32_16x16x32_bf16(A0, Bf[t][0], acc[t], 0,0,0);
      acc[t] = __builtin_amdgcn_mfma_f32_16x16x32_bf16(A1, Bf[t][1], acc[t], 0,0,0);
    }
    // fc1-edge stash: slot-ordered compact rows of 16 floats (sequential)
    if (c < 14) {
      #pragma unroll
      for (int r = 0; r < 4; r++)
        stash_s[(size_t)(s0 + kb*4 + r)*16 + c] = acc[8][r];
    }
    // per-slot broadcast (slot = kb*4+r)
    int sN[4], dN[4]; float wd[4];
    #pragma unroll
    for (int r = 0; r < 4; r++) {
      sN[r] = __shfl(sNv, kb*4 + r, 64);
      dN[r] = __shfl(dNv, kb*4 + r, 64);
      wd[r] = __shfl(wdv, kb*4 + r, 64);
    }
    unsigned vdu[4][4], vsu[4][4];
    #pragma unroll
    for (int r = 0; r < 4; r++) {
      #pragma unroll
      for (int t = 0; t < 4; t++) {
        vdu[r][t] = P2u[(size_t)dN[r]*128 + t*16 + c];          // dst: L2-hot
        vsu[r][t] = P2u[(size_t)sN[r]*128 + 64 + t*16 + c];     // src: random
      }
    }
    #pragma unroll
    for (int r = 0; r < 4; r++) {
      #pragma unroll
      for (int t = 0; t < 4; t++) {
        float zf = acc[t][r]   + lo16f(vdu[r][t]) + lo16f(vsu[r][t]) + bfo[t];
        float zs = acc[t+4][r] + hi16f(vdu[r][t]) + hi16f(vsu[r][t]) + bso[t];
        float m = sigm(zf) * sofp(zs) * wd[r];
        atomicAdd(&aout[(size_t)dN[r]*FF + t*16 + c], m);       // line-clustered
      }
    }
  }
}

// ---------------------------------------------------------------------------
// k3: per-node fc1 partials on UPDATED node features.  C padded to 32/row
// (128B = one cache line) so k5's src-gathers fetch exactly one line.
// ---------------------------------------------------------------------------
__global__ __launch_bounds__(256) void k3_cpre(
    const float* __restrict__ aout, const float* __restrict__ fc1w,
    float* __restrict__ C)
{
  __shared__ float wT[64*32];
  __shared__ float xs[4][64];
  int tid = threadIdx.x;
  for (int i = tid; i < 64*28; i += 256) {
    int k = i / 28, j = i % 28;
    wT[k*32 + j] = (j < 14) ? fc1w[j*ZD + k] : fc1w[(j-14)*ZD + 64 + k];
  }
  __syncthreads();
  int o  = tid & 63;
  int lw = tid >> 6;
  int wid = blockIdx.x * 4 + lw;
  int nw  = gridDim.x * 4;
  for (int n = wid; n < NN; n += nw) {
    xs[lw][o] = aout[(size_t)n*FF + o];
    float acc = 0.f;
    if (o < 28) {
      for (int k = 0; k < 64; k++) acc += xs[lw][k] * wT[k*32 + o];
      C[n*32 + o] = acc;
    }
  }
}

// ---------------------------------------------------------------------------
// k5: slot-major edge-update MLP.  Sequential meta+stash; C-dst clustered;
// full-row coalesced eout writes.
// ---------------------------------------------------------------------------
__global__ __launch_bounds__(256) void k5_edge_mlp(
    const int4* __restrict__ meta,
    const float* __restrict__ fc1b,
    const float* __restrict__ fc2w, const float* __restrict__ fc2b,
    const float* __restrict__ C, const float* __restrict__ stash_s,
    float* __restrict__ eout)
{
  __shared__ float w2T[14*64];
  __shared__ float hs[4][128];
  __shared__ int   eids[4][8];
  int tid = threadIdx.x;
  for (int i = tid; i < 14*64; i += 256) {
    int j = i >> 6, o = i & 63;
    w2T[i] = fc2w[o*14 + j];
  }
  __syncthreads();
  int o  = tid & 63;
  int lw = tid >> 6;
  int j4 = o >> 2, q = o & 3;
  int wid = blockIdx.x*4 + lw;
  int nw  = gridDim.x*4;
  for (int g = wid; g < NE/8; g += nw) {
    int s0 = g*8;
    #pragma unroll
    for (int pass = 0; pass < 2; pass++) {
      int ee = pass*4 + q;
      int s = s0 + ee;
      int4 mv = meta[s];
      if (j4 == 0) eids[lw][ee] = mv.x;
      if (j4 < 14) {
        float h = stash_s[(size_t)s*16 + j4] + C[(size_t)mv.y*32 + j4]
                + C[(size_t)mv.z*32 + 14 + j4] + fc1b[j4];
        hs[lw][ee*16 + j4] = fsilu(h);
      }
    }
    asm volatile("s_waitcnt lgkmcnt(0)" ::: "memory");  // in-wave LDS RAW
    float b2 = fc2b[o];
    #pragma unroll
    for (int ee = 0; ee < 8; ee++) {
      float acc = b2;
      #pragma unroll
      for (int jj = 0; jj < 14; jj++)
        acc += w2T[jj*64 + o] * hs[lw][ee*16 + jj];
      eout[(size_t)eids[lw][ee]*FF + o] = fsilu(acc);
    }
  }
}

// ---------------------------------------------------------------------------
extern "C" void kernel_launch(void* const* d_in, const int* in_sizes, int n_in,
                              void* d_out, int out_size, void* d_ws, size_t ws_size,
                              hipStream_t stream) {
  const float* atom  = (const float*)d_in[0];
  const int*   eidx  = (const int*)  d_in[1];
  const float* efea  = (const float*)d_in[2];
  const float* dist  = (const float*)d_in[4];
  const float* wf    = (const float*)d_in[6];
  const float* bf    = (const float*)d_in[7];
  const float* ws    = (const float*)d_in[8];
  const float* bs    = (const float*)d_in[9];
  const float* fc1w  = (const float*)d_in[10];
  const float* fc1b  = (const float*)d_in[11];
  const float* fc2w  = (const float*)d_in[12];
  const float* fc2b  = (const float*)d_in[13];

  float* aout = (float*)d_out;                 // [50000, 64]
  float* eout = aout + (size_t)NN * FF;        // [800000, 64]

  char* wp = (char*)d_ws;
  unsigned* P2u    = (unsigned*)wp;  wp += (size_t)NN * 128 * 4;   // 25.6 MB
  float*    C      = (float*)wp;     wp += (size_t)NN * 32 * 4;    //  6.4 MB
  int*      cnt    = (int*)wp;       wp += (size_t)(NN + 64) * 4;
  int*      off    = (int*)wp;       wp += (size_t)(NN + 64) * 4;
  int*      cur    = (int*)wp;       wp += (size_t)(NN + 64) * 4;
  int4*     meta   = (int4*)wp;      wp += (size_t)NE * 16;        // 12.8 MB
  float*    stash  = (float*)wp;     wp += (size_t)NE * 16 * 4;    // 51.2 MB

  hipLaunchKernelGGL(kz,     dim3((NN+255)/256), dim3(256), 0, stream, cnt);
  hipLaunchKernelGGL(kh,     dim3((NE+255)/256), dim3(256), 0, stream, eidx, cnt);
  hipLaunchKernelGGL(kscan,  dim3(1), dim3(1024), 0, stream, cnt, off, cur);
  hipLaunchKernelGGL(kscat2, dim3((NE+255)/256), dim3(256), 0, stream, eidx, dist, cur, meta);

  hipLaunchKernelGGL(k1_node_pre, dim3(512), dim3(256), 0, stream,
                     atom, wf, ws, P2u, aout);
  hipLaunchKernelGGL(k2_msg, dim3(2048), dim3(256), 0, stream,
                     meta, efea, wf, ws, bf, bs, fc1w, P2u, aout, stash);
  hipLaunchKernelGGL(k3_cpre, dim3(512), dim3(256), 0, stream,
                     aout, fc1w, C);
  hipLaunchKernelGGL(k5_edge_mlp, dim3(2048), dim3(256), 0, stream,
                     meta, fc1b, fc2w, fc2b, C, stash, eout);
}

// Round 10
// 403.791 us; speedup vs baseline: 2.6866x; 2.6866x over previous
//
#include <hip/hip_runtime.h>
#include <hip/hip_bf16.h>
#include <math.h>

#define NN 50000
#define NE 800000
#define FF 64
#define ZD 192

typedef __attribute__((ext_vector_type(8))) short bf16x8;
typedef __attribute__((ext_vector_type(4))) float f32x4;

__device__ __forceinline__ short f2bs(float f){
  union { __hip_bfloat16 h; short s; } u; u.h = __float2bfloat16(f); return u.s;
}
__device__ __forceinline__ unsigned packbf(float a, float b){
  return ((unsigned)(unsigned short)f2bs(b) << 16) | (unsigned)(unsigned short)f2bs(a);
}
__device__ __forceinline__ float lo16f(unsigned u){ union{unsigned u; float f;} v; v.u = u << 16; return v.f; }
__device__ __forceinline__ float hi16f(unsigned u){ union{unsigned u; float f;} v; v.u = u & 0xFFFF0000u; return v.f; }
__device__ __forceinline__ float sigm(float x){ return 1.0f/(1.0f+__expf(-x)); }
__device__ __forceinline__ float sofp(float x){ return fmaxf(x,0.0f)+__logf(1.0f+__expf(-fabsf(x))); }
__device__ __forceinline__ float fsilu(float x){ return x/(1.0f+__expf(-x)); }

// ---------------------------------------------------------------------------
// k1: aout=atom copy + per-node gating-linear parts via MFMA (packed bf16).
//  P2u[n*128 + o] = pack(Af,As) ; P2u[n*128+64+o] = pack(Bf,Bs)
// ---------------------------------------------------------------------------
__global__ __launch_bounds__(256) void k1_node_pre(
    const float* __restrict__ atom,
    const float* __restrict__ wf, const float* __restrict__ ws,
    unsigned* __restrict__ P2u, float* __restrict__ aout)
{
  int tid0 = blockIdx.x * 256 + threadIdx.x;
  int nthr = gridDim.x * 256;
  const float4* a4 = (const float4*)atom;
  float4* o4 = (float4*)aout;
  for (int i = tid0; i < NN*FF/4; i += nthr) o4[i] = a4[i];

  int lane = threadIdx.x & 63;
  int c = lane & 15, kb = lane >> 4;
  int wid = blockIdx.x * 4 + (threadIdx.x >> 6);
  int nw = gridDim.x * 4;
  for (int g = wid; g < NN/16; g += nw) {
    int n0 = g * 16;
    const float* arow = &atom[(size_t)(n0 + c) * FF + kb*8];
    bf16x8 A0, A1;
    #pragma unroll
    for (int j = 0; j < 8; j++) { A0[j] = f2bs(arow[j]); A1[j] = f2bs(arow[32+j]); }
    f32x4 acc[16];
    #pragma unroll
    for (int t = 0; t < 16; t++) acc[t] = (f32x4){0,0,0,0};
    #pragma unroll
    for (int t = 0; t < 16; t++) {
      int og = t*16 + c;
      const float* src;
      if (t < 4)       src = &wf[og*ZD];
      else if (t < 8)  src = &wf[(og-64)*ZD + 64];
      else if (t < 12) src = &ws[(og-128)*ZD];
      else             src = &ws[(og-192)*ZD + 64];
      bf16x8 B0, B1;
      #pragma unroll
      for (int j = 0; j < 8; j++) { B0[j] = f2bs(src[kb*8+j]); B1[j] = f2bs(src[32+kb*8+j]); }
      acc[t] = __builtin_amdgcn_mfma_f32_16x16x32_bf16(A0, B0, acc[t], 0,0,0);
      acc[t] = __builtin_amdgcn_mfma_f32_16x16x32_bf16(A1, B1, acc[t], 0,0,0);
    }
    #pragma unroll
    for (int t = 0; t < 8; t++) {
      #pragma unroll
      for (int r = 0; r < 4; r++) {
        int n = n0 + kb*4 + r;
        P2u[(size_t)n*128 + t*16 + c] = packbf(acc[t][r], acc[t+8][r]);
      }
    }
  }
}

// ---------------------------------------------------------------------------
// k2: R5 monolith + cross-iteration prefetch (single change vs R5).
//  FIFO order per iter: [consume prefetched streams] -> [P2 gathers g] ->
//  [prefetch streams g+1] -> MFMA -> stash -> epilogue(wait gathers; prefetch
//  stays outstanding) -> atomics (issued last; retired behind next iter's
//  waits only after a full iteration of slack).
// ---------------------------------------------------------------------------
__global__ __launch_bounds__(256) void k2_msg(
    const int* __restrict__ eidx, const float* __restrict__ efea,
    const float* __restrict__ dist,
    const float* __restrict__ wf, const float* __restrict__ ws,
    const float* __restrict__ bfb, const float* __restrict__ bsb,
    const float* __restrict__ fc1w,
    const unsigned* __restrict__ P2u, float* __restrict__ aout,
    float* __restrict__ eout)
{
  int tid = threadIdx.x;
  int lane = tid & 63;
  int lw = tid >> 6;
  int c = lane & 15, kb = lane >> 4;

  bf16x8 Bf[9][2];
  #pragma unroll
  for (int t = 0; t < 9; t++) {
    int og = t*16 + c;
    const float* src = nullptr;
    if (t < 4)            src = &wf[og*ZD + 128];
    else if (t < 8)       src = &ws[(og-64)*ZD + 128];
    else if (og-128 < 14) src = &fc1w[(og-128)*ZD + 128];
    #pragma unroll
    for (int f = 0; f < 2; f++) {
      bf16x8 r;
      #pragma unroll
      for (int j = 0; j < 8; j++) r[j] = src ? f2bs(src[f*32 + kb*8 + j]) : (short)0;
      Bf[t][f] = r;
    }
  }
  float bfo[4], bso[4];
  #pragma unroll
  for (int t = 0; t < 4; t++) { bfo[t] = bfb[t*16+c]; bso[t] = bsb[t*16+c]; }

  const int ngroups = NE/16;
  int wid = blockIdx.x*4 + lw;
  int nw = gridDim.x*4;

  // prefetched streams for group g
  int pS = 0, pD = 0; float pDe = 0.f;
  float4 pe0, pe1, pe2, pe3;
  int g = wid;
  if (g < ngroups) {
    int e0 = g*16;
    pS  = eidx[e0 + c];
    pD  = eidx[NE + e0 + c];
    pDe = dist[e0 + c];
    const float4* er = (const float4*)&efea[(size_t)(e0 + c)*FF];
    pe0 = er[kb*2]; pe1 = er[kb*2+1]; pe2 = er[8+kb*2]; pe3 = er[8+kb*2+1];
  }

  for (; g < ngroups; g += nw) {
    int e0 = g*16;
    // consume prefetched streams
    bf16x8 A0, A1;
    A0[0]=f2bs(pe0.x); A0[1]=f2bs(pe0.y); A0[2]=f2bs(pe0.z); A0[3]=f2bs(pe0.w);
    A0[4]=f2bs(pe1.x); A0[5]=f2bs(pe1.y); A0[6]=f2bs(pe1.z); A0[7]=f2bs(pe1.w);
    A1[0]=f2bs(pe2.x); A1[1]=f2bs(pe2.y); A1[2]=f2bs(pe2.z); A1[3]=f2bs(pe2.w);
    A1[4]=f2bs(pe3.x); A1[5]=f2bs(pe3.y); A1[6]=f2bs(pe3.z); A1[7]=f2bs(pe3.w);
    int sNv = pS, dNv = pD; float dev = pDe;
    float wdv = __expf(-dev*dev*(1.0f/18.0f));
    int sN[4], dN[4]; float wd[4];
    #pragma unroll
    for (int r = 0; r < 4; r++) {
      sN[r] = __shfl(sNv, kb*4 + r, 64);
      dN[r] = __shfl(dNv, kb*4 + r, 64);
      wd[r] = __shfl(wdv, kb*4 + r, 64);
    }
    // P2 gathers for g (issued before prefetch so their wait keeps prefetch outstanding)
    unsigned vdu[4][4], vsu[4][4];
    #pragma unroll
    for (int r = 0; r < 4; r++) {
      #pragma unroll
      for (int t = 0; t < 4; t++) {
        vdu[r][t] = P2u[(size_t)dN[r]*128 + t*16 + c];
        vsu[r][t] = P2u[(size_t)sN[r]*128 + 64 + t*16 + c];
      }
    }
    // prefetch streams for g+1
    {
      int gp = g + nw; if (gp >= ngroups) gp = g;
      int e0p = gp*16;
      pS  = eidx[e0p + c];
      pD  = eidx[NE + e0p + c];
      pDe = dist[e0p + c];
      const float4* erp = (const float4*)&efea[(size_t)(e0p + c)*FF];
      pe0 = erp[kb*2]; pe1 = erp[kb*2+1]; pe2 = erp[8+kb*2]; pe3 = erp[8+kb*2+1];
    }
    // MFMA over 9 output tiles (A,B in regs -> no memory waits)
    f32x4 acc[9];
    #pragma unroll
    for (int t = 0; t < 9; t++) acc[t] = (f32x4){0,0,0,0};
    #pragma unroll
    for (int t = 0; t < 9; t++) {
      acc[t] = __builtin_amdgcn_mfma_f32_16x16x32_bf16(A0, Bf[t][0], acc[t], 0,0,0);
      acc[t] = __builtin_amdgcn_mfma_f32_16x16x32_bf16(A1, Bf[t][1], acc[t], 0,0,0);
    }
    // fc1-edge stash: D row = edge = kb*4+r, col = j = c
    if (c < 14) {
      #pragma unroll
      for (int r = 0; r < 4; r++)
        eout[(size_t)(e0 + kb*4 + r)*FF + c] = acc[8][r];
    }
    // epilogue (waits gathers), then atomics issued last
    #pragma unroll
    for (int r = 0; r < 4; r++) {
      #pragma unroll
      for (int t = 0; t < 4; t++) {
        float zf = acc[t][r]   + lo16f(vdu[r][t]) + lo16f(vsu[r][t]) + bfo[t];
        float zs = acc[t+4][r] + hi16f(vdu[r][t]) + hi16f(vsu[r][t]) + bso[t];
        float m = sigm(zf) * sofp(zs) * wd[r];
        atomicAdd(&aout[(size_t)dN[r]*FF + t*16 + c], m);
      }
    }
  }
}

// ---------------------------------------------------------------------------
// k3: per-node fc1 partials on UPDATED node features.
// ---------------------------------------------------------------------------
__global__ __launch_bounds__(256) void k3_cpre(
    const float* __restrict__ aout, const float* __restrict__ fc1w,
    float* __restrict__ C)
{
  __shared__ float wT[64*32];
  __shared__ float xs[4][64];
  int tid = threadIdx.x;
  for (int i = tid; i < 64*28; i += 256) {
    int k = i / 28, j = i % 28;
    wT[k*32 + j] = (j < 14) ? fc1w[j*ZD + k] : fc1w[(j-14)*ZD + 64 + k];
  }
  __syncthreads();
  int o  = tid & 63;
  int lw = tid >> 6;
  int wid = blockIdx.x * 4 + lw;
  int nw  = gridDim.x * 4;
  for (int n = wid; n < NN; n += nw) {
    xs[lw][o] = aout[(size_t)n*FF + o];
    float acc = 0.f;
    if (o < 28) {
      for (int k = 0; k < 64; k++) acc += xs[lw][k] * wT[k*32 + o];
      C[n*28 + o] = acc;
    }
  }
}

// ---------------------------------------------------------------------------
// k5: edge-update MLP. 8 edges/wave. h-edge-part read from eout stash.
// ---------------------------------------------------------------------------
__global__ __launch_bounds__(256) void k5_edge_mlp(
    const int* __restrict__ eidx,
    const float* __restrict__ fc1b,
    const float* __restrict__ fc2w, const float* __restrict__ fc2b,
    const float* __restrict__ C, float* __restrict__ eout)
{
  __shared__ float w2T[14*64];
  __shared__ float hs[4][128];
  int tid = threadIdx.x;
  for (int i = tid; i < 14*64; i += 256) {
    int j = i >> 6, o = i & 63;
    w2T[i] = fc2w[o*14 + j];
  }
  __syncthreads();
  int o  = tid & 63;
  int lw = tid >> 6;
  int j4 = o >> 2, q = o & 3;
  int wid = blockIdx.x*4 + lw;
  int nw  = gridDim.x*4;
  for (int g = wid; g < NE/8; g += nw) {
    int e0 = g*8;
    #pragma unroll
    for (int pass = 0; pass < 2; pass++) {
      int ee = pass*4 + q;
      int e = e0 + ee;
      if (j4 < 14) {
        int sN = eidx[e], dN = eidx[NE+e];
        float h = eout[(size_t)e*FF + j4] + C[sN*28 + j4] + C[dN*28 + 14 + j4] + fc1b[j4];
        hs[lw][ee*16 + j4] = fsilu(h);
      }
    }
    asm volatile("s_waitcnt lgkmcnt(0)" ::: "memory");  // in-wave LDS RAW
    float b2 = fc2b[o];
    #pragma unroll
    for (int ee = 0; ee < 8; ee++) {
      float acc = b2;
      #pragma unroll
      for (int jj = 0; jj < 14; jj++)
        acc += w2T[jj*64 + o] * hs[lw][ee*16 + jj];
      eout[(size_t)(e0 + ee)*FF + o] = fsilu(acc);
    }
  }
}

// ---------------------------------------------------------------------------
extern "C" void kernel_launch(void* const* d_in, const int* in_sizes, int n_in,
                              void* d_out, int out_size, void* d_ws, size_t ws_size,
                              hipStream_t stream) {
  const float* atom  = (const float*)d_in[0];
  const int*   eidx  = (const int*)  d_in[1];
  const float* efea  = (const float*)d_in[2];
  const float* dist  = (const float*)d_in[4];
  const float* wf    = (const float*)d_in[6];
  const float* bf    = (const float*)d_in[7];
  const float* ws    = (const float*)d_in[8];
  const float* bs    = (const float*)d_in[9];
  const float* fc1w  = (const float*)d_in[10];
  const float* fc1b  = (const float*)d_in[11];
  const float* fc2w  = (const float*)d_in[12];
  const float* fc2b  = (const float*)d_in[13];

  float* aout = (float*)d_out;                 // [50000, 64]
  float* eout = aout + (size_t)NN * FF;        // [800000, 64]

  unsigned* P2u = (unsigned*)d_ws;                              // 25.6 MB
  float*    C   = (float*)((char*)d_ws + (size_t)NN * 128 * 4); // +5.6 MB

  hipLaunchKernelGGL(k1_node_pre, dim3(512), dim3(256), 0, stream,
                     atom, wf, ws, P2u, aout);
  hipLaunchKernelGGL(k2_msg, dim3(1024), dim3(256), 0, stream,
                     eidx, efea, dist, wf, ws, bf, bs, fc1w, P2u, aout, eout);
  hipLaunchKernelGGL(k3_cpre, dim3(512), dim3(256), 0, stream,
                     aout, fc1w, C);
  hipLaunchKernelGGL(k5_edge_mlp, dim3(2048), dim3(256), 0, stream,
                     eidx, fc1b, fc2w, fc2b, C, eout);
}